// Round 1
// baseline (6519.334 us; speedup 1.0000x reference)
//
#include <hip/hip_runtime.h>
#include <math.h>

#define FLAT 65536

// ---------------------------------------------------------------------------
// conv3x3 + bias + relu.  IC = input channels (128 for conv1 concat, 64 for
// conv2).  DUAL: channels >=64 come from src1.  Each block: one frame (bt),
// one 8-row stripe, 256 threads = 32x8 pixels, each thread accumulates all 64
// output channels in registers.  Weights are wave-uniform -> scalar loads.
// ---------------------------------------------------------------------------
template<int IC, bool DUAL>
__global__ __launch_bounds__(256) void conv3x3_relu_kernel(
    const float* __restrict__ src0, const float* __restrict__ src1,
    const float* __restrict__ w, const float* __restrict__ bias,
    float* __restrict__ dst)
{
    const int bt = blockIdx.x;
    const int y0 = blockIdx.y * 8;
    const int tx = threadIdx.x & 31;
    const int ty = threadIdx.x >> 5;

    __shared__ float tile[8][10][34];   // [ic-chunk][row(y0-1..y0+8)][col(-1..32)]

    float acc[64];
#pragma unroll
    for (int i = 0; i < 64; ++i) acc[i] = 0.f;

    for (int icc = 0; icc < IC; icc += 8) {
        __syncthreads();
        for (int idx = threadIdx.x; idx < 8 * 10 * 34; idx += 256) {
            int lc  = idx / 340;
            int rem = idx - lc * 340;
            int ry  = rem / 34;
            int rx  = rem - ry * 34;
            int gy  = y0 - 1 + ry;
            int gx  = rx - 1;
            int ic  = icc + lc;
            float v = 0.f;
            if (gy >= 0 && gy < 32 && gx >= 0 && gx < 32) {
                const float* s = src0;
                int c = ic;
                if (DUAL && ic >= 64) { s = src1; c = ic - 64; }
                v = s[((size_t)bt * 64 + c) * 1024 + gy * 32 + gx];
            }
            tile[lc][ry][rx] = v;
        }
        __syncthreads();
        for (int lc = 0; lc < 8; ++lc) {
            float v[9];
#pragma unroll
            for (int ky = 0; ky < 3; ++ky)
#pragma unroll
                for (int kx = 0; kx < 3; ++kx)
                    v[ky * 3 + kx] = tile[lc][ty + ky][tx + kx];
            const float* wp = w + (size_t)(icc + lc) * 9;
#pragma unroll
            for (int oc = 0; oc < 64; ++oc) {
                const float* wo = wp + (size_t)oc * (IC * 9);
                float a = acc[oc];
#pragma unroll
                for (int k = 0; k < 9; ++k) a = fmaf(wo[k], v[k], a);
                acc[oc] = a;
            }
        }
    }
    const int y = y0 + ty;
#pragma unroll
    for (int oc = 0; oc < 64; ++oc) {
        float r = acc[oc] + bias[oc];
        dst[((size_t)bt * 64 + oc) * 1024 + y * 32 + tx] = r > 0.f ? r : 0.f;
    }
}

// ---------------------------------------------------------------------------
// fc1: out[r][j] = dot(Z[r, :], W[j, :]) over K=65536, split-K = 8.
// Z rows 0..255 = conv output (mbuf), rows 256..511 = f_t flat.
// 64x64 block tile, 256 threads, 4x4 micro-tile, KT=16, LDS [k][row].
// ---------------------------------------------------------------------------
__global__ __launch_bounds__(256) void fc1_gemm_kernel(
    const float* __restrict__ mbuf, const float* __restrict__ f_t,
    const float* __restrict__ w, float* __restrict__ part)
{
    const int row0 = blockIdx.x * 64;
    const int col0 = blockIdx.y * 64;
    const int ks   = blockIdx.z;
    const size_t kbase = (size_t)ks * 8192;

    __shared__ __align__(16) float As[16][64];
    __shared__ __align__(16) float Ws[16][64];

    const int tx = threadIdx.x & 15;
    const int ty = threadIdx.x >> 4;

    float acc[4][4] = {};

    const float* Abase = (row0 < 256) ? (mbuf + (size_t)row0 * FLAT)
                                      : (f_t + (size_t)(row0 - 256) * FLAT);
    const int r  = threadIdx.x >> 2;
    const int kq = (threadIdx.x & 3) * 4;
    const float* ap = Abase + (size_t)r * FLAT + kbase + kq;
    const float* wp = w + (size_t)(col0 + r) * FLAT + kbase + kq;

    for (int kk = 0; kk < 8192; kk += 16) {
        float4 va = *(const float4*)(ap + kk);
        float4 vw = *(const float4*)(wp + kk);
        __syncthreads();
        As[kq + 0][r] = va.x; As[kq + 1][r] = va.y; As[kq + 2][r] = va.z; As[kq + 3][r] = va.w;
        Ws[kq + 0][r] = vw.x; Ws[kq + 1][r] = vw.y; Ws[kq + 2][r] = vw.z; Ws[kq + 3][r] = vw.w;
        __syncthreads();
#pragma unroll
        for (int k = 0; k < 16; ++k) {
            float a4[4], w4[4];
            *(float4*)a4 = *(const float4*)&As[k][ty * 4];
            *(float4*)w4 = *(const float4*)&Ws[k][tx * 4];
#pragma unroll
            for (int i = 0; i < 4; ++i)
#pragma unroll
                for (int j = 0; j < 4; ++j)
                    acc[i][j] = fmaf(a4[i], w4[j], acc[i][j]);
        }
    }
    float* op = part + ((size_t)ks * 512 + row0 + ty * 4) * 1024 + col0 + tx * 4;
#pragma unroll
    for (int i = 0; i < 4; ++i)
#pragma unroll
        for (int j = 0; j < 4; ++j)
            op[(size_t)i * 1024 + j] = acc[i][j];
}

__global__ __launch_bounds__(256) void fc1_reduce_kernel(
    const float* __restrict__ part, const float* __restrict__ bias,
    float* __restrict__ h)
{
    int idx = blockIdx.x * 256 + threadIdx.x;     // 0..524287
    int j = idx & 1023;
    float s = bias[j];
#pragma unroll
    for (int ks = 0; ks < 8; ++ks) s += part[(size_t)ks * 524288 + idx];
    h[idx] = s > 0.f ? s : 0.f;
}

// ---------------------------------------------------------------------------
// fc2 + attention epilogue.  M=512 (mot rows 0..255, app rows 256..511),
// N=512, K=1024.  Epilogue computes alpha (stored to d_out) and builds the
// time-major LSTM inputs in_m / in_a.
// ---------------------------------------------------------------------------
__global__ __launch_bounds__(256) void fc2_att_kernel(
    const float* __restrict__ h, const float* __restrict__ w,
    const float* __restrict__ bias,
    const float* __restrict__ att1, const float* __restrict__ att2,
    float* __restrict__ alpha_out, float* __restrict__ inm, float* __restrict__ ina)
{
    const int row0 = blockIdx.x * 64;
    const int col0 = blockIdx.y * 64;

    __shared__ __align__(16) float As[16][64];
    __shared__ __align__(16) float Ws[16][64];

    const int tx = threadIdx.x & 15;
    const int ty = threadIdx.x >> 4;
    float acc[4][4] = {};

    const int r  = threadIdx.x >> 2;
    const int kq = (threadIdx.x & 3) * 4;
    const float* ap = h + (size_t)(row0 + r) * 1024 + kq;
    const float* wp = w + (size_t)(col0 + r) * 1024 + kq;

    for (int kk = 0; kk < 1024; kk += 16) {
        float4 va = *(const float4*)(ap + kk);
        float4 vw = *(const float4*)(wp + kk);
        __syncthreads();
        As[kq + 0][r] = va.x; As[kq + 1][r] = va.y; As[kq + 2][r] = va.z; As[kq + 3][r] = va.w;
        Ws[kq + 0][r] = vw.x; Ws[kq + 1][r] = vw.y; Ws[kq + 2][r] = vw.z; Ws[kq + 3][r] = vw.w;
        __syncthreads();
#pragma unroll
        for (int k = 0; k < 16; ++k) {
            float a4[4], w4[4];
            *(float4*)a4 = *(const float4*)&As[k][ty * 4];
            *(float4*)w4 = *(const float4*)&Ws[k][tx * 4];
#pragma unroll
            for (int i = 0; i < 4; ++i)
#pragma unroll
                for (int j = 0; j < 4; ++j)
                    acc[i][j] = fmaf(a4[i], w4[j], acc[i][j]);
        }
    }
#pragma unroll
    for (int i = 0; i < 4; ++i) {
        int row = row0 + ty * 4 + i;
        int bt  = (row < 256) ? row : row - 256;
        int b = bt >> 4, t = bt & 15;
#pragma unroll
        for (int j = 0; j < 4; ++j) {
            int jj = col0 + tx * 4 + j;
            float v = acc[i][j] + bias[jj];
            size_t ibase = ((size_t)t * 16 + b) * 1024;
            if (row < 256) {   // mot path
                float al = 1.f / (1.f + expf(-att1[b * 512 + jj] * v));
                alpha_out[(size_t)bt * 512 + jj] = al;
                inm[ibase + jj]       = al * v;
                inm[ibase + 512 + jj] = v;
            } else {           // app path
                float be = 1.f / (1.f + expf(-att2[b * 512 + jj] * v));
                ina[ibase + jj]       = be * v;
                ina[ibase + 512 + jj] = v;
            }
        }
    }
}

// ---------------------------------------------------------------------------
// gx: precompute the x-projection of LSTM cell-1 gates for ALL timesteps.
// gx[row][n] = dot(in[row,:], wih[n,:]) + bih[n] + bhh[n];  M=256, N=2048,
// K=1024, path z: 0 = m, 1 = a.
// ---------------------------------------------------------------------------
__global__ __launch_bounds__(256) void gx_gemm_kernel(
    const float* __restrict__ inm, const float* __restrict__ ina,
    const float* __restrict__ wih_m, const float* __restrict__ bih_m, const float* __restrict__ bhh_m,
    const float* __restrict__ wih_a, const float* __restrict__ bih_a, const float* __restrict__ bhh_a,
    float* __restrict__ gxm, float* __restrict__ gxa)
{
    const int row0 = blockIdx.x * 64;
    const int col0 = blockIdx.y * 64;
    const int path = blockIdx.z;

    const float* A  = path ? ina : inm;
    const float* W  = path ? wih_a : wih_m;
    const float* bi = path ? bih_a : bih_m;
    const float* bh = path ? bhh_a : bhh_m;
    float* out = path ? gxa : gxm;

    __shared__ __align__(16) float As[16][64];
    __shared__ __align__(16) float Ws[16][64];

    const int tx = threadIdx.x & 15;
    const int ty = threadIdx.x >> 4;
    float acc[4][4] = {};

    const int r  = threadIdx.x >> 2;
    const int kq = (threadIdx.x & 3) * 4;
    const float* ap = A + (size_t)(row0 + r) * 1024 + kq;
    const float* wp = W + (size_t)(col0 + r) * 1024 + kq;

    for (int kk = 0; kk < 1024; kk += 16) {
        float4 va = *(const float4*)(ap + kk);
        float4 vw = *(const float4*)(wp + kk);
        __syncthreads();
        As[kq + 0][r] = va.x; As[kq + 1][r] = va.y; As[kq + 2][r] = va.z; As[kq + 3][r] = va.w;
        Ws[kq + 0][r] = vw.x; Ws[kq + 1][r] = vw.y; Ws[kq + 2][r] = vw.z; Ws[kq + 3][r] = vw.w;
        __syncthreads();
#pragma unroll
        for (int k = 0; k < 16; ++k) {
            float a4[4], w4[4];
            *(float4*)a4 = *(const float4*)&As[k][ty * 4];
            *(float4*)w4 = *(const float4*)&Ws[k][tx * 4];
#pragma unroll
            for (int i = 0; i < 4; ++i)
#pragma unroll
                for (int j = 0; j < 4; ++j)
                    acc[i][j] = fmaf(a4[i], w4[j], acc[i][j]);
        }
    }
#pragma unroll
    for (int i = 0; i < 4; ++i)
#pragma unroll
        for (int j = 0; j < 4; ++j) {
            int jj = col0 + tx * 4 + j;
            out[(size_t)(row0 + ty * 4 + i) * 2048 + jj] = acc[i][j] + bi[jj] + bh[jj];
        }
}

// cell2m has x == h, so pre-sum its wih+whh and bih+bhh.
__global__ void w2sum_kernel(const float* __restrict__ a, const float* __restrict__ b,
                             const float* __restrict__ ba, const float* __restrict__ bb,
                             float* __restrict__ w, float* __restrict__ bs)
{
    int i = blockIdx.x * 256 + threadIdx.x;
    if (i < 2048 * 512) w[i] = a[i] + b[i];
    if (i < 2048) bs[i] = ba[i] + bb[i];
}

// ---------------------------------------------------------------------------
// LSTM stage 1 (cells l1m, l1a):  g = gx[t] + h_old @ whh^T, then gate
// nonlinearities; writes new s1/c1 and the first half of the outputs.
// Block: (jtile of 16 hidden units, path); thread = (b, jj), owns all 4 gates.
// ---------------------------------------------------------------------------
__global__ __launch_bounds__(256) void lstm_stage1_kernel(
    int t,
    const float* __restrict__ gxm, const float* __restrict__ gxa,
    const float* __restrict__ whh_m, const float* __restrict__ whh_a,
    const float* __restrict__ s1m_in, float* __restrict__ s1m_out,
    const float* __restrict__ s1a_in, float* __restrict__ s1a_out,
    float* __restrict__ c1m, float* __restrict__ c1a,
    float* __restrict__ out)
{
    const int path = blockIdx.y;         // 0 = m, 1 = a
    const int j0 = blockIdx.x * 16;
    const int b  = threadIdx.x >> 4;
    const int jj = threadIdx.x & 15;
    const int j  = j0 + jj;

    const float* gx   = path ? gxa : gxm;
    const float* whh  = path ? whh_a : whh_m;
    const float* sin_ = path ? s1a_in : s1m_in;
    float* sout = path ? s1a_out : s1m_out;
    float* cbuf = path ? c1a : c1m;

    __shared__ __align__(16) float hs[16][516];
    for (int idx = threadIdx.x; idx < 8192; idx += 256)
        hs[idx >> 9][idx & 511] = sin_[idx];
    __syncthreads();

    float g[4];
#pragma unroll
    for (int q = 0; q < 4; ++q)
        g[q] = gx[((size_t)(t * 16 + b)) * 2048 + q * 512 + j];

    const float* w0 = whh + (size_t)(0 * 512 + j) * 512;
    const float* w1 = whh + (size_t)(1 * 512 + j) * 512;
    const float* w2 = whh + (size_t)(2 * 512 + j) * 512;
    const float* w3 = whh + (size_t)(3 * 512 + j) * 512;
    for (int k = 0; k < 512; k += 4) {
        float hv[4], v0[4], v1[4], v2[4], v3[4];
        *(float4*)hv = *(const float4*)&hs[b][k];
        *(float4*)v0 = *(const float4*)(w0 + k);
        *(float4*)v1 = *(const float4*)(w1 + k);
        *(float4*)v2 = *(const float4*)(w2 + k);
        *(float4*)v3 = *(const float4*)(w3 + k);
#pragma unroll
        for (int u = 0; u < 4; ++u) {
            g[0] = fmaf(hv[u], v0[u], g[0]);
            g[1] = fmaf(hv[u], v1[u], g[1]);
            g[2] = fmaf(hv[u], v2[u], g[2]);
            g[3] = fmaf(hv[u], v3[u], g[3]);
        }
    }
    float i_ = 1.f / (1.f + expf(-g[0]));
    float f_ = 1.f / (1.f + expf(-g[1]));
    float gg = tanhf(g[2]);
    float o_ = 1.f / (1.f + expf(-g[3]));
    float c = f_ * cbuf[b * 512 + j] + i_ * gg;
    cbuf[b * 512 + j] = c;
    float hval = o_ * tanhf(c);
    sout[b * 512 + j] = hval;
    size_t obase = path ? 0 : 262144;    // out_a first, then out_m
    out[obase + ((size_t)b * 16 + t) * 1024 + j] = hval;
}

// ---------------------------------------------------------------------------
// LSTM stage 2 (cells l2m, l2a).  m: g = b2m + s1m @ (wih+whh)^T (x==h).
// a: g = bih+bhh + s1a @ wih^T + s2a_old @ whh^T.
// ---------------------------------------------------------------------------
__global__ __launch_bounds__(256) void lstm_stage2_kernel(
    int t,
    const float* __restrict__ w2m, const float* __restrict__ b2m,
    const float* __restrict__ w2a_ih, const float* __restrict__ w2a_hh,
    const float* __restrict__ b2a_ih, const float* __restrict__ b2a_hh,
    const float* __restrict__ s1m, const float* __restrict__ s1a,
    const float* __restrict__ s2a_in, float* __restrict__ s2a_out,
    float* __restrict__ c2m, float* __restrict__ c2a,
    float* __restrict__ out)
{
    const int path = blockIdx.y;         // 0 = m, 1 = a
    const int j0 = blockIdx.x * 16;
    const int b  = threadIdx.x >> 4;
    const int jj = threadIdx.x & 15;
    const int j  = j0 + jj;

    __shared__ __align__(16) float xs[16][516];
    __shared__ __align__(16) float hs[16][516];

    const float* xsrc = path ? s1a : s1m;
    for (int idx = threadIdx.x; idx < 8192; idx += 256)
        xs[idx >> 9][idx & 511] = xsrc[idx];
    if (path) {
        for (int idx = threadIdx.x; idx < 8192; idx += 256)
            hs[idx >> 9][idx & 511] = s2a_in[idx];
    }
    __syncthreads();

    float g[4];
    if (path) {
#pragma unroll
        for (int q = 0; q < 4; ++q) g[q] = b2a_ih[q * 512 + j] + b2a_hh[q * 512 + j];
    } else {
#pragma unroll
        for (int q = 0; q < 4; ++q) g[q] = b2m[q * 512 + j];
    }

    const float* wx = path ? w2a_ih : w2m;
    {
        const float* w0 = wx + (size_t)(0 * 512 + j) * 512;
        const float* w1 = wx + (size_t)(1 * 512 + j) * 512;
        const float* w2 = wx + (size_t)(2 * 512 + j) * 512;
        const float* w3 = wx + (size_t)(3 * 512 + j) * 512;
        for (int k = 0; k < 512; k += 4) {
            float hv[4], v0[4], v1[4], v2[4], v3[4];
            *(float4*)hv = *(const float4*)&xs[b][k];
            *(float4*)v0 = *(const float4*)(w0 + k);
            *(float4*)v1 = *(const float4*)(w1 + k);
            *(float4*)v2 = *(const float4*)(w2 + k);
            *(float4*)v3 = *(const float4*)(w3 + k);
#pragma unroll
            for (int u = 0; u < 4; ++u) {
                g[0] = fmaf(hv[u], v0[u], g[0]);
                g[1] = fmaf(hv[u], v1[u], g[1]);
                g[2] = fmaf(hv[u], v2[u], g[2]);
                g[3] = fmaf(hv[u], v3[u], g[3]);
            }
        }
    }
    if (path) {
        const float* w0 = w2a_hh + (size_t)(0 * 512 + j) * 512;
        const float* w1 = w2a_hh + (size_t)(1 * 512 + j) * 512;
        const float* w2 = w2a_hh + (size_t)(2 * 512 + j) * 512;
        const float* w3 = w2a_hh + (size_t)(3 * 512 + j) * 512;
        for (int k = 0; k < 512; k += 4) {
            float hv[4], v0[4], v1[4], v2[4], v3[4];
            *(float4*)hv = *(const float4*)&hs[b][k];
            *(float4*)v0 = *(const float4*)(w0 + k);
            *(float4*)v1 = *(const float4*)(w1 + k);
            *(float4*)v2 = *(const float4*)(w2 + k);
            *(float4*)v3 = *(const float4*)(w3 + k);
#pragma unroll
            for (int u = 0; u < 4; ++u) {
                g[0] = fmaf(hv[u], v0[u], g[0]);
                g[1] = fmaf(hv[u], v1[u], g[1]);
                g[2] = fmaf(hv[u], v2[u], g[2]);
                g[3] = fmaf(hv[u], v3[u], g[3]);
            }
        }
    }

    float* cbuf = path ? c2a : c2m;
    float i_ = 1.f / (1.f + expf(-g[0]));
    float f_ = 1.f / (1.f + expf(-g[1]));
    float gg = tanhf(g[2]);
    float o_ = 1.f / (1.f + expf(-g[3]));
    float c = f_ * cbuf[b * 512 + j] + i_ * gg;
    cbuf[b * 512 + j] = c;
    float hval = o_ * tanhf(c);
    if (path) {
        s2a_out[b * 512 + j] = hval;
        out[((size_t)b * 16 + t) * 1024 + 512 + j] = hval;            // out_a[:,:,512+j]
    } else {
        out[262144 + ((size_t)b * 16 + t) * 1024 + 512 + j] = hval;   // out_m[:,:,512+j]
    }
}

// ---------------------------------------------------------------------------
extern "C" void kernel_launch(void* const* d_in, const int* in_sizes, int n_in,
                              void* d_out, int out_size, void* d_ws, size_t ws_size,
                              hipStream_t stream)
{
    (void)in_sizes; (void)n_in; (void)out_size; (void)ws_size;
    const float* f_t     = (const float*)d_in[0];
    const float* f_t_1   = (const float*)d_in[1];
    const float* att1    = (const float*)d_in[2];
    const float* att2    = (const float*)d_in[3];
    const float* conv1_w = (const float*)d_in[4];
    const float* conv1_b = (const float*)d_in[5];
    const float* conv2_w = (const float*)d_in[6];
    const float* conv2_b = (const float*)d_in[7];
    const float* l1a_wih = (const float*)d_in[8];
    const float* l1a_whh = (const float*)d_in[9];
    const float* l1a_bih = (const float*)d_in[10];
    const float* l1a_bhh = (const float*)d_in[11];
    const float* l2a_wih = (const float*)d_in[12];
    const float* l2a_whh = (const float*)d_in[13];
    const float* l2a_bih = (const float*)d_in[14];
    const float* l2a_bhh = (const float*)d_in[15];
    const float* l1m_wih = (const float*)d_in[16];
    const float* l1m_whh = (const float*)d_in[17];
    const float* l1m_bih = (const float*)d_in[18];
    const float* l1m_bhh = (const float*)d_in[19];
    const float* l2m_wih = (const float*)d_in[20];
    const float* l2m_whh = (const float*)d_in[21];
    const float* l2m_bih = (const float*)d_in[22];
    const float* l2m_bhh = (const float*)d_in[23];
    const float* fc1_w   = (const float*)d_in[24];
    const float* fc1_b   = (const float*)d_in[25];
    const float* fc2_w   = (const float*)d_in[26];
    const float* fc2_b   = (const float*)d_in[27];

    float* ws   = (float*)d_ws;
    float* tmp1 = ws;                       // 16777216  conv1 out
    float* mbuf = tmp1 + 16777216;          // 16777216  conv2 out (motion)
    float* part = mbuf + 16777216;          // 4194304   fc1 split-K partials
    float* hbuf = part + 4194304;           // 524288    relu(fc1) [512][1024]
    float* inm  = hbuf + 524288;            // 262144    [t][b][1024]
    float* ina  = inm + 262144;             // 262144
    float* gxm  = ina + 262144;             // 524288    [t*16+b][2048]
    float* gxa  = gxm + 524288;             // 524288
    float* w2m  = gxa + 524288;             // 1048576   l2m wih+whh
    float* b2m  = w2m + 1048576;            // 2048
    float* st   = b2m + 2048;               // states: 81920 floats
    float* s1m  = st;                       // [2][16][512]
    float* s1a  = s1m + 16384;              // [2][16][512]
    float* s2a  = s1a + 16384;              // [2][16][512]
    float* c1m  = s2a + 16384;              // [16][512]
    float* c1a  = c1m + 8192;
    float* c2m  = c1a + 8192;
    float* c2a  = c2m + 8192;

    float* outp = (float*)d_out;
    float* alpha_out = outp + 524288;       // after outs_a (262144) + outs_m (262144)

    // zero LSTM initial states (both ping-pong buffers + cell states)
    hipMemsetAsync(st, 0, 81920 * sizeof(float), stream);

    conv3x3_relu_kernel<128, true ><<<dim3(256, 4), 256, 0, stream>>>(f_t, f_t_1, conv1_w, conv1_b, tmp1);
    conv3x3_relu_kernel< 64, false><<<dim3(256, 4), 256, 0, stream>>>(tmp1, nullptr, conv2_w, conv2_b, mbuf);

    fc1_gemm_kernel<<<dim3(8, 16, 8), 256, 0, stream>>>(mbuf, f_t, fc1_w, part);
    fc1_reduce_kernel<<<2048, 256, 0, stream>>>(part, fc1_b, hbuf);

    fc2_att_kernel<<<dim3(8, 8), 256, 0, stream>>>(hbuf, fc2_w, fc2_b, att1, att2,
                                                   alpha_out, inm, ina);

    gx_gemm_kernel<<<dim3(4, 32, 2), 256, 0, stream>>>(inm, ina,
                                                       l1m_wih, l1m_bih, l1m_bhh,
                                                       l1a_wih, l1a_bih, l1a_bhh,
                                                       gxm, gxa);
    w2sum_kernel<<<4096, 256, 0, stream>>>(l2m_wih, l2m_whh, l2m_bih, l2m_bhh, w2m, b2m);

    for (int t = 0; t < 16; ++t) {
        const float* s1m_in = s1m + (t & 1) * 8192;
        float*       s1m_o  = s1m + ((t + 1) & 1) * 8192;
        const float* s1a_in = s1a + (t & 1) * 8192;
        float*       s1a_o  = s1a + ((t + 1) & 1) * 8192;
        const float* s2a_in = s2a + (t & 1) * 8192;
        float*       s2a_o  = s2a + ((t + 1) & 1) * 8192;
        lstm_stage1_kernel<<<dim3(32, 2), 256, 0, stream>>>(
            t, gxm, gxa, l1m_whh, l1a_whh,
            s1m_in, s1m_o, s1a_in, s1a_o, c1m, c1a, outp);
        lstm_stage2_kernel<<<dim3(32, 2), 256, 0, stream>>>(
            t, w2m, b2m, l2a_wih, l2a_whh, l2a_bih, l2a_bhh,
            s1m_o, s1a_o, s2a_in, s2a_o, c2m, c2a, outp);
    }
}

// Round 2
// 3319.564 us; speedup vs baseline: 1.9639x; 1.9639x over previous
//
#include <hip/hip_runtime.h>
#include <math.h>
#include <stdint.h>

typedef __attribute__((ext_vector_type(8))) short    bf16x8;
typedef __attribute__((ext_vector_type(4))) float    f32x4;
typedef __attribute__((ext_vector_type(8))) uint16_t u16x8;

__device__ __forceinline__ uint16_t f2bf(float f) {
    union { float f; uint32_t u; } v; v.f = f;
    uint32_t r = v.u + 0x7FFFu + ((v.u >> 16) & 1u);
    return (uint16_t)(r >> 16);
}

// ---------------------------------------------------------------------------
// prep: f_t (fp32 flat NCHW) -> bf16 flat (fc1 A rows 256..511)
// ---------------------------------------------------------------------------
__global__ __launch_bounds__(256) void cvt_flat_kernel(
    const float* __restrict__ src, uint16_t* __restrict__ dst, int n)
{
    int i = (blockIdx.x * 256 + threadIdx.x) * 8;
    if (i >= n) return;
    float4 a = *(const float4*)(src + i);
    float4 b = *(const float4*)(src + i + 4);
    u16x8 o;
    o[0] = f2bf(a.x); o[1] = f2bf(a.y); o[2] = f2bf(a.z); o[3] = f2bf(a.w);
    o[4] = f2bf(b.x); o[5] = f2bf(b.y); o[6] = f2bf(b.z); o[7] = f2bf(b.w);
    *(u16x8*)(dst + i) = o;
}

// ---------------------------------------------------------------------------
// prep: concat(f_t, f_t_1) NCHW fp32 -> NHWC bf16 [bt][y][x][128]
// block: (bt, ctile 32, pxtile 256), LDS transpose.
// ---------------------------------------------------------------------------
__global__ __launch_bounds__(256) void nhwc_kernel(
    const float* __restrict__ f_t, const float* __restrict__ f_t_1,
    uint16_t* __restrict__ dst)
{
    __shared__ float lds[32][258];
    const int bt  = blockIdx.y;
    const int c0  = (blockIdx.x >> 2) * 32;
    const int px0 = (blockIdx.x & 3) * 256;
    const int t   = threadIdx.x;

    const int lc  = t & 31;          // local c
    const int lpx = (t >> 5) * 32;   // local px base (8 groups of 32)
    const int c   = c0 + lc;
    const float* src = (c < 64)
        ? (f_t   + ((size_t)bt * 64 + c) * 1024)
        : (f_t_1 + ((size_t)bt * 64 + (c - 64)) * 1024);
#pragma unroll
    for (int j = 0; j < 32; j += 4) {
        float4 v = *(const float4*)(src + px0 + lpx + j);
        lds[lc][lpx + j + 0] = v.x;
        lds[lc][lpx + j + 1] = v.y;
        lds[lc][lpx + j + 2] = v.z;
        lds[lc][lpx + j + 3] = v.w;
    }
    __syncthreads();
    uint16_t* op = dst + ((size_t)bt * 1024 + px0 + t) * 128 + c0;
#pragma unroll
    for (int u0 = 0; u0 < 32; u0 += 8) {
        u16x8 o;
#pragma unroll
        for (int u = 0; u < 8; ++u) o[u] = f2bf(lds[u0 + u][t]);
        *(u16x8*)(op + u0) = o;
    }
}

// ---------------------------------------------------------------------------
// prep: conv weights [64][IC][3][3] fp32 -> packed bf16 [oc][(ky*3+kx)*IC + c]
// ---------------------------------------------------------------------------
__global__ __launch_bounds__(256) void wpack_kernel(
    const float* __restrict__ w1, const float* __restrict__ w2,
    uint16_t* __restrict__ p1, uint16_t* __restrict__ p2)
{
    int i = blockIdx.x * 256 + threadIdx.x;
    if (i < 64 * 1152) {
        int oc = i / 1152, k = i - oc * 1152;
        int s = k >> 7, c = k & 127;
        int ky = s / 3, kx = s - ky * 3;
        p1[i] = f2bf(w1[((oc * 128 + c) * 3 + ky) * 3 + kx]);
    }
    if (i < 64 * 576) {
        int oc = i / 576, k = i - oc * 576;
        int s = k >> 6, c = k & 63;
        int ky = s / 3, kx = s - ky * 3;
        p2[i] = f2bf(w2[((oc * 64 + c) * 3 + ky) * 3 + kx]);
    }
}

// ---------------------------------------------------------------------------
// conv3x3 + bias + relu as implicit-GEMM MFMA.
// A = pixels [128][k], B = wpack [64 oc][k], K = 9*IC (tap-major, c-minor).
// SWAP=false: C[pixel][oc], out NHWC bf16 (conv1 -> conv2 input).
// SWAP=true : C[oc][pixel], out NCHW bf16 (conv2 -> fc1 A rows).
// grid (8 pxtiles, 256 frames), 256 threads = 4 waves; wave owns 32 pixels.
// ---------------------------------------------------------------------------
template<int IC, bool SWAP>
__global__ __launch_bounds__(256) void conv_mfma_kernel(
    const uint16_t* __restrict__ in_nhwc,  // [bt][32][32][IC]
    const uint16_t* __restrict__ wpack,    // [64][9*IC]
    const float* __restrict__ bias,
    uint16_t* __restrict__ out)
{
    constexpr int KT  = 9 * IC;
    constexpr int CPS = IC / 32;          // c-chunks per tap
    constexpr int MF  = SWAP ? 4 : 2;
    constexpr int NF  = SWAP ? 2 : 4;

    __shared__ __align__(16) uint16_t Apx[128 * 32];
    __shared__ __align__(16) uint16_t Bw[64 * 32];

    const int bt  = blockIdx.y;
    const int px0 = blockIdx.x * 128;
    const int t   = threadIdx.x;
    const int w   = t >> 6, l = t & 63;

    // A staging: thread -> (pixel m, c-half)
    const int m = t >> 1, chalf = (t & 1) * 16;
    const int y = (px0 + m) >> 5, x = m & 31;
    // B staging: thread -> (oc, k-slot)
    const int oc_s = t >> 2, kslot = t & 3;

    f32x4 acc[MF][NF] = {};

    for (int q = 0; q < 9 * CPS; ++q) {
        const int s  = q / CPS, cc = (q - s * CPS) * 32;
        const int ky = s / 3,  kx = s - ky * 3;
        const int yy = y + ky - 1, xx = x + kx - 1;
        const bool ok = (yy >= 0) & (yy < 32) & (xx >= 0) & (xx < 32);
        u16x8 a0 = {}, a1 = {};
        if (ok) {
            const uint16_t* sp = in_nhwc
                + (((size_t)bt * 1024) + yy * 32 + xx) * IC + cc + chalf;
            a0 = *(const u16x8*)sp;
            a1 = *(const u16x8*)(sp + 8);
        }
        u16x8 b0 = *(const u16x8*)(wpack + (size_t)oc_s * KT + q * 32 + kslot * 8);

        __syncthreads();
        *(u16x8*)(Apx + m * 32 + chalf)     = a0;
        *(u16x8*)(Apx + m * 32 + chalf + 8) = a1;
        *(u16x8*)(Bw + oc_s * 32 + kslot * 8) = b0;
        __syncthreads();

        const int row = l & 15, kg = (l >> 4) * 8;
        if (!SWAP) {
            bf16x8 af[2], bf[4];
#pragma unroll
            for (int i = 0; i < 2; ++i)
                af[i] = *(const bf16x8*)(Apx + (w * 32 + i * 16 + row) * 32 + kg);
#pragma unroll
            for (int j = 0; j < 4; ++j)
                bf[j] = *(const bf16x8*)(Bw + (j * 16 + row) * 32 + kg);
#pragma unroll
            for (int i = 0; i < MF; ++i)
#pragma unroll
                for (int j = 0; j < NF; ++j)
                    acc[i][j] = __builtin_amdgcn_mfma_f32_16x16x32_bf16(
                        af[i], bf[j], acc[i][j], 0, 0, 0);
        } else {
            bf16x8 af[4], bf[2];
#pragma unroll
            for (int i = 0; i < 4; ++i)
                af[i] = *(const bf16x8*)(Bw + (i * 16 + row) * 32 + kg);
#pragma unroll
            for (int j = 0; j < 2; ++j)
                bf[j] = *(const bf16x8*)(Apx + (w * 32 + j * 16 + row) * 32 + kg);
#pragma unroll
            for (int i = 0; i < MF; ++i)
#pragma unroll
                for (int j = 0; j < NF; ++j)
                    acc[i][j] = __builtin_amdgcn_mfma_f32_16x16x32_bf16(
                        af[i], bf[j], acc[i][j], 0, 0, 0);
        }
    }

    const int col = l & 15, rg = (l >> 4) * 4;
    if (!SWAP) {
#pragma unroll
        for (int i = 0; i < 2; ++i)
#pragma unroll
            for (int j = 0; j < 4; ++j) {
                const int ocb = j * 16 + col;
                const float bv = bias[ocb];
#pragma unroll
                for (int r = 0; r < 4; ++r) {
                    const int px = px0 + w * 32 + i * 16 + rg + r;
                    float v = acc[i][j][r] + bv; v = v > 0.f ? v : 0.f;
                    out[((size_t)bt * 1024 + px) * 64 + ocb] = f2bf(v);
                }
            }
    } else {
#pragma unroll
        for (int i = 0; i < 4; ++i)
#pragma unroll
            for (int j = 0; j < 2; ++j)
#pragma unroll
                for (int r = 0; r < 4; ++r) {
                    const int oc = i * 16 + rg + r;
                    const int px = px0 + w * 32 + j * 16 + col;
                    float v = acc[i][j][r] + bias[oc]; v = v > 0.f ? v : 0.f;
                    out[((size_t)bt * 64 + oc) * 1024 + px] = f2bf(v);
                }
    }
}

// ---------------------------------------------------------------------------
// fc1 MFMA: part[ks][r][j] = dot(Z[r, kseg], W[j, kseg]); K=65536, S=16.
// Z rows 0..255 = conv2 bf16 out (NCHW flat), rows 256..511 = f_t bf16 flat.
// BM=128, BN=128, BK=32, 4 waves, wave = 64x64 (4x4 frags).
// ---------------------------------------------------------------------------
__global__ __launch_bounds__(256) void fc1_mfma_kernel(
    const uint16_t* __restrict__ Am, const uint16_t* __restrict__ Af,
    const float* __restrict__ Wf, float* __restrict__ part)
{
    __shared__ __align__(16) uint16_t Aa[128 * 32];
    __shared__ __align__(16) uint16_t Bb[128 * 32];

    const int row0 = blockIdx.x * 128;
    const int col0 = blockIdx.y * 128;
    const int ks   = blockIdx.z;
    const size_t kbase = (size_t)ks * 4096;
    const uint16_t* Abase = (row0 < 256) ? (Am + (size_t)row0 * 65536)
                                         : (Af + (size_t)(row0 - 256) * 65536);

    const int t = threadIdx.x;
    const int w = t >> 6, l = t & 63;
    const int wr = (w >> 1) * 64, wc = (w & 1) * 64;

    const int srow  = t >> 1;           // A row / B col within tile
    const int shalf = (t & 1) * 16;     // k half
    const uint16_t* ap = Abase + (size_t)srow * 65536 + kbase + shalf;
    const float*    bp = Wf + (size_t)(col0 + srow) * 65536 + kbase + shalf;
    uint16_t* awr = Aa + srow * 32 + shalf;
    uint16_t* bwr = Bb + srow * 32 + shalf;

    f32x4 acc[4][4] = {};

    for (int kk = 0; kk < 4096; kk += 32) {
        u16x8 a0 = *(const u16x8*)(ap + kk);
        u16x8 a1 = *(const u16x8*)(ap + kk + 8);
        float4 f0 = *(const float4*)(bp + kk);
        float4 f1 = *(const float4*)(bp + kk + 4);
        float4 f2 = *(const float4*)(bp + kk + 8);
        float4 f3 = *(const float4*)(bp + kk + 12);
        u16x8 b0, b1;
        b0[0] = f2bf(f0.x); b0[1] = f2bf(f0.y); b0[2] = f2bf(f0.z); b0[3] = f2bf(f0.w);
        b0[4] = f2bf(f1.x); b0[5] = f2bf(f1.y); b0[6] = f2bf(f1.z); b0[7] = f2bf(f1.w);
        b1[0] = f2bf(f2.x); b1[1] = f2bf(f2.y); b1[2] = f2bf(f2.z); b1[3] = f2bf(f2.w);
        b1[4] = f2bf(f3.x); b1[5] = f2bf(f3.y); b1[6] = f2bf(f3.z); b1[7] = f2bf(f3.w);

        __syncthreads();
        *(u16x8*)awr       = a0;
        *(u16x8*)(awr + 8) = a1;
        *(u16x8*)bwr       = b0;
        *(u16x8*)(bwr + 8) = b1;
        __syncthreads();

        const int row = l & 15, kg = (l >> 4) * 8;
        bf16x8 afr[4], bfr[4];
#pragma unroll
        for (int i = 0; i < 4; ++i)
            afr[i] = *(const bf16x8*)(Aa + (wr + i * 16 + row) * 32 + kg);
#pragma unroll
        for (int j = 0; j < 4; ++j)
            bfr[j] = *(const bf16x8*)(Bb + (wc + j * 16 + row) * 32 + kg);
#pragma unroll
        for (int i = 0; i < 4; ++i)
#pragma unroll
            for (int j = 0; j < 4; ++j)
                acc[i][j] = __builtin_amdgcn_mfma_f32_16x16x32_bf16(
                    afr[i], bfr[j], acc[i][j], 0, 0, 0);
    }

    const int col = l & 15, rg = (l >> 4) * 4;
#pragma unroll
    for (int i = 0; i < 4; ++i)
#pragma unroll
        for (int r = 0; r < 4; ++r) {
            const int grow = row0 + wr + i * 16 + rg + r;
            float* op = part + ((size_t)ks * 512 + grow) * 1024 + col0 + wc + col;
#pragma unroll
            for (int j = 0; j < 4; ++j) op[j * 16] = acc[i][j][r];
        }
}

__global__ __launch_bounds__(256) void fc1_reduce_kernel(
    const float* __restrict__ part, const float* __restrict__ bias,
    float* __restrict__ h)
{
    int idx = blockIdx.x * 256 + threadIdx.x;     // 0..524287
    int j = idx & 1023;
    float s = bias[j];
#pragma unroll
    for (int ks = 0; ks < 16; ++ks) s += part[(size_t)ks * 524288 + idx];
    h[idx] = s > 0.f ? s : 0.f;
}

// ---------------------------------------------------------------------------
// fc2 + attention epilogue (fp32).  M=512 (mot 0..255, app 256..511), N=512,
// K=1024.  Epilogue computes alpha and builds time-major LSTM inputs.
// ---------------------------------------------------------------------------
__global__ __launch_bounds__(256) void fc2_att_kernel(
    const float* __restrict__ h, const float* __restrict__ w,
    const float* __restrict__ bias,
    const float* __restrict__ att1, const float* __restrict__ att2,
    float* __restrict__ alpha_out, float* __restrict__ inm, float* __restrict__ ina)
{
    const int row0 = blockIdx.x * 64;
    const int col0 = blockIdx.y * 64;

    __shared__ __align__(16) float As[16][64];
    __shared__ __align__(16) float Ws[16][64];

    const int tx = threadIdx.x & 15;
    const int ty = threadIdx.x >> 4;
    float acc[4][4] = {};

    const int r  = threadIdx.x >> 2;
    const int kq = (threadIdx.x & 3) * 4;
    const float* ap = h + (size_t)(row0 + r) * 1024 + kq;
    const float* wp = w + (size_t)(col0 + r) * 1024 + kq;

    for (int kk = 0; kk < 1024; kk += 16) {
        float4 va = *(const float4*)(ap + kk);
        float4 vw = *(const float4*)(wp + kk);
        __syncthreads();
        As[kq + 0][r] = va.x; As[kq + 1][r] = va.y; As[kq + 2][r] = va.z; As[kq + 3][r] = va.w;
        Ws[kq + 0][r] = vw.x; Ws[kq + 1][r] = vw.y; Ws[kq + 2][r] = vw.z; Ws[kq + 3][r] = vw.w;
        __syncthreads();
#pragma unroll
        for (int k = 0; k < 16; ++k) {
            float a4[4], w4[4];
            *(float4*)a4 = *(const float4*)&As[k][ty * 4];
            *(float4*)w4 = *(const float4*)&Ws[k][tx * 4];
#pragma unroll
            for (int i = 0; i < 4; ++i)
#pragma unroll
                for (int j = 0; j < 4; ++j)
                    acc[i][j] = fmaf(a4[i], w4[j], acc[i][j]);
        }
    }
#pragma unroll
    for (int i = 0; i < 4; ++i) {
        int row = row0 + ty * 4 + i;
        int bt  = (row < 256) ? row : row - 256;
        int b = bt >> 4, t = bt & 15;
#pragma unroll
        for (int j = 0; j < 4; ++j) {
            int jj = col0 + tx * 4 + j;
            float v = acc[i][j] + bias[jj];
            size_t ibase = ((size_t)t * 16 + b) * 1024;
            if (row < 256) {   // mot path
                float al = 1.f / (1.f + expf(-att1[b * 512 + jj] * v));
                alpha_out[(size_t)bt * 512 + jj] = al;
                inm[ibase + jj]       = al * v;
                inm[ibase + 512 + jj] = v;
            } else {           // app path
                float be = 1.f / (1.f + expf(-att2[b * 512 + jj] * v));
                ina[ibase + jj]       = be * v;
                ina[ibase + 512 + jj] = v;
            }
        }
    }
}

// ---------------------------------------------------------------------------
// gx: x-projection of LSTM cell-1 gates for all timesteps (fp32).
// ---------------------------------------------------------------------------
__global__ __launch_bounds__(256) void gx_gemm_kernel(
    const float* __restrict__ inm, const float* __restrict__ ina,
    const float* __restrict__ wih_m, const float* __restrict__ bih_m, const float* __restrict__ bhh_m,
    const float* __restrict__ wih_a, const float* __restrict__ bih_a, const float* __restrict__ bhh_a,
    float* __restrict__ gxm, float* __restrict__ gxa)
{
    const int row0 = blockIdx.x * 64;
    const int col0 = blockIdx.y * 64;
    const int path = blockIdx.z;

    const float* A  = path ? ina : inm;
    const float* W  = path ? wih_a : wih_m;
    const float* bi = path ? bih_a : bih_m;
    const float* bh = path ? bhh_a : bhh_m;
    float* out = path ? gxa : gxm;

    __shared__ __align__(16) float As[16][64];
    __shared__ __align__(16) float Ws[16][64];

    const int tx = threadIdx.x & 15;
    const int ty = threadIdx.x >> 4;
    float acc[4][4] = {};

    const int r  = threadIdx.x >> 2;
    const int kq = (threadIdx.x & 3) * 4;
    const float* ap = A + (size_t)(row0 + r) * 1024 + kq;
    const float* wp = W + (size_t)(col0 + r) * 1024 + kq;

    for (int kk = 0; kk < 1024; kk += 16) {
        float4 va = *(const float4*)(ap + kk);
        float4 vw = *(const float4*)(wp + kk);
        __syncthreads();
        As[kq + 0][r] = va.x; As[kq + 1][r] = va.y; As[kq + 2][r] = va.z; As[kq + 3][r] = va.w;
        Ws[kq + 0][r] = vw.x; Ws[kq + 1][r] = vw.y; Ws[kq + 2][r] = vw.z; Ws[kq + 3][r] = vw.w;
        __syncthreads();
#pragma unroll
        for (int k = 0; k < 16; ++k) {
            float a4[4], w4[4];
            *(float4*)a4 = *(const float4*)&As[k][ty * 4];
            *(float4*)w4 = *(const float4*)&Ws[k][tx * 4];
#pragma unroll
            for (int i = 0; i < 4; ++i)
#pragma unroll
                for (int j = 0; j < 4; ++j)
                    acc[i][j] = fmaf(a4[i], w4[j], acc[i][j]);
        }
    }
#pragma unroll
    for (int i = 0; i < 4; ++i)
#pragma unroll
        for (int j = 0; j < 4; ++j) {
            int jj = col0 + tx * 4 + j;
            out[(size_t)(row0 + ty * 4 + i) * 2048 + jj] = acc[i][j] + bi[jj] + bh[jj];
        }
}

// cell2m has x == h, so pre-sum its wih+whh and bih+bhh.
__global__ void w2sum_kernel(const float* __restrict__ a, const float* __restrict__ b,
                             const float* __restrict__ ba, const float* __restrict__ bb,
                             float* __restrict__ w, float* __restrict__ bs)
{
    int i = blockIdx.x * 256 + threadIdx.x;
    if (i < 2048 * 512) w[i] = a[i] + b[i];
    if (i < 2048) bs[i] = ba[i] + bb[i];
}

// ---------------------------------------------------------------------------
// LSTM stage 1 (cells l1m, l1a), fp32.
// ---------------------------------------------------------------------------
__global__ __launch_bounds__(256) void lstm_stage1_kernel(
    int t,
    const float* __restrict__ gxm, const float* __restrict__ gxa,
    const float* __restrict__ whh_m, const float* __restrict__ whh_a,
    const float* __restrict__ s1m_in, float* __restrict__ s1m_out,
    const float* __restrict__ s1a_in, float* __restrict__ s1a_out,
    float* __restrict__ c1m, float* __restrict__ c1a,
    float* __restrict__ out)
{
    const int path = blockIdx.y;
    const int j0 = blockIdx.x * 16;
    const int b  = threadIdx.x >> 4;
    const int jj = threadIdx.x & 15;
    const int j  = j0 + jj;

    const float* gx   = path ? gxa : gxm;
    const float* whh  = path ? whh_a : whh_m;
    const float* sin_ = path ? s1a_in : s1m_in;
    float* sout = path ? s1a_out : s1m_out;
    float* cbuf = path ? c1a : c1m;

    __shared__ __align__(16) float hs[16][516];
    for (int idx = threadIdx.x; idx < 8192; idx += 256)
        hs[idx >> 9][idx & 511] = sin_[idx];
    __syncthreads();

    float g[4];
#pragma unroll
    for (int q = 0; q < 4; ++q)
        g[q] = gx[((size_t)(t * 16 + b)) * 2048 + q * 512 + j];

    const float* w0 = whh + (size_t)(0 * 512 + j) * 512;
    const float* w1 = whh + (size_t)(1 * 512 + j) * 512;
    const float* w2 = whh + (size_t)(2 * 512 + j) * 512;
    const float* w3 = whh + (size_t)(3 * 512 + j) * 512;
    for (int k = 0; k < 512; k += 4) {
        float hv[4], v0[4], v1[4], v2[4], v3[4];
        *(float4*)hv = *(const float4*)&hs[b][k];
        *(float4*)v0 = *(const float4*)(w0 + k);
        *(float4*)v1 = *(const float4*)(w1 + k);
        *(float4*)v2 = *(const float4*)(w2 + k);
        *(float4*)v3 = *(const float4*)(w3 + k);
#pragma unroll
        for (int u = 0; u < 4; ++u) {
            g[0] = fmaf(hv[u], v0[u], g[0]);
            g[1] = fmaf(hv[u], v1[u], g[1]);
            g[2] = fmaf(hv[u], v2[u], g[2]);
            g[3] = fmaf(hv[u], v3[u], g[3]);
        }
    }
    float i_ = 1.f / (1.f + expf(-g[0]));
    float f_ = 1.f / (1.f + expf(-g[1]));
    float gg = tanhf(g[2]);
    float o_ = 1.f / (1.f + expf(-g[3]));
    float c = f_ * cbuf[b * 512 + j] + i_ * gg;
    cbuf[b * 512 + j] = c;
    float hval = o_ * tanhf(c);
    sout[b * 512 + j] = hval;
    size_t obase = path ? 0 : 262144;
    out[obase + ((size_t)b * 16 + t) * 1024 + j] = hval;
}

// ---------------------------------------------------------------------------
// LSTM stage 2 (cells l2m, l2a), fp32.
// ---------------------------------------------------------------------------
__global__ __launch_bounds__(256) void lstm_stage2_kernel(
    int t,
    const float* __restrict__ w2m, const float* __restrict__ b2m,
    const float* __restrict__ w2a_ih, const float* __restrict__ w2a_hh,
    const float* __restrict__ b2a_ih, const float* __restrict__ b2a_hh,
    const float* __restrict__ s1m, const float* __restrict__ s1a,
    const float* __restrict__ s2a_in, float* __restrict__ s2a_out,
    float* __restrict__ c2m, float* __restrict__ c2a,
    float* __restrict__ out)
{
    const int path = blockIdx.y;
    const int j0 = blockIdx.x * 16;
    const int b  = threadIdx.x >> 4;
    const int jj = threadIdx.x & 15;
    const int j  = j0 + jj;

    __shared__ __align__(16) float xs[16][516];
    __shared__ __align__(16) float hs[16][516];

    const float* xsrc = path ? s1a : s1m;
    for (int idx = threadIdx.x; idx < 8192; idx += 256)
        xs[idx >> 9][idx & 511] = xsrc[idx];
    if (path) {
        for (int idx = threadIdx.x; idx < 8192; idx += 256)
            hs[idx >> 9][idx & 511] = s2a_in[idx];
    }
    __syncthreads();

    float g[4];
    if (path) {
#pragma unroll
        for (int q = 0; q < 4; ++q) g[q] = b2a_ih[q * 512 + j] + b2a_hh[q * 512 + j];
    } else {
#pragma unroll
        for (int q = 0; q < 4; ++q) g[q] = b2m[q * 512 + j];
    }

    const float* wx = path ? w2a_ih : w2m;
    {
        const float* w0 = wx + (size_t)(0 * 512 + j) * 512;
        const float* w1 = wx + (size_t)(1 * 512 + j) * 512;
        const float* w2 = wx + (size_t)(2 * 512 + j) * 512;
        const float* w3 = wx + (size_t)(3 * 512 + j) * 512;
        for (int k = 0; k < 512; k += 4) {
            float hv[4], v0[4], v1[4], v2[4], v3[4];
            *(float4*)hv = *(const float4*)&xs[b][k];
            *(float4*)v0 = *(const float4*)(w0 + k);
            *(float4*)v1 = *(const float4*)(w1 + k);
            *(float4*)v2 = *(const float4*)(w2 + k);
            *(float4*)v3 = *(const float4*)(w3 + k);
#pragma unroll
            for (int u = 0; u < 4; ++u) {
                g[0] = fmaf(hv[u], v0[u], g[0]);
                g[1] = fmaf(hv[u], v1[u], g[1]);
                g[2] = fmaf(hv[u], v2[u], g[2]);
                g[3] = fmaf(hv[u], v3[u], g[3]);
            }
        }
    }
    if (path) {
        const float* w0 = w2a_hh + (size_t)(0 * 512 + j) * 512;
        const float* w1 = w2a_hh + (size_t)(1 * 512 + j) * 512;
        const float* w2 = w2a_hh + (size_t)(2 * 512 + j) * 512;
        const float* w3 = w2a_hh + (size_t)(3 * 512 + j) * 512;
        for (int k = 0; k < 512; k += 4) {
            float hv[4], v0[4], v1[4], v2[4], v3[4];
            *(float4*)hv = *(const float4*)&hs[b][k];
            *(float4*)v0 = *(const float4*)(w0 + k);
            *(float4*)v1 = *(const float4*)(w1 + k);
            *(float4*)v2 = *(const float4*)(w2 + k);
            *(float4*)v3 = *(const float4*)(w3 + k);
#pragma unroll
            for (int u = 0; u < 4; ++u) {
                g[0] = fmaf(hv[u], v0[u], g[0]);
                g[1] = fmaf(hv[u], v1[u], g[1]);
                g[2] = fmaf(hv[u], v2[u], g[2]);
                g[3] = fmaf(hv[u], v3[u], g[3]);
            }
        }
    }

    float* cbuf = path ? c2a : c2m;
    float i_ = 1.f / (1.f + expf(-g[0]));
    float f_ = 1.f / (1.f + expf(-g[1]));
    float gg = tanhf(g[2]);
    float o_ = 1.f / (1.f + expf(-g[3]));
    float c = f_ * cbuf[b * 512 + j] + i_ * gg;
    cbuf[b * 512 + j] = c;
    float hval = o_ * tanhf(c);
    if (path) {
        s2a_out[b * 512 + j] = hval;
        out[((size_t)b * 16 + t) * 1024 + 512 + j] = hval;
    } else {
        out[262144 + ((size_t)b * 16 + t) * 1024 + 512 + j] = hval;
    }
}

// ---------------------------------------------------------------------------
extern "C" void kernel_launch(void* const* d_in, const int* in_sizes, int n_in,
                              void* d_out, int out_size, void* d_ws, size_t ws_size,
                              hipStream_t stream)
{
    (void)in_sizes; (void)n_in; (void)out_size; (void)ws_size;
    const float* f_t     = (const float*)d_in[0];
    const float* f_t_1   = (const float*)d_in[1];
    const float* att1    = (const float*)d_in[2];
    const float* att2    = (const float*)d_in[3];
    const float* conv1_w = (const float*)d_in[4];
    const float* conv1_b = (const float*)d_in[5];
    const float* conv2_w = (const float*)d_in[6];
    const float* conv2_b = (const float*)d_in[7];
    const float* l1a_wih = (const float*)d_in[8];
    const float* l1a_whh = (const float*)d_in[9];
    const float* l1a_bih = (const float*)d_in[10];
    const float* l1a_bhh = (const float*)d_in[11];
    const float* l2a_wih = (const float*)d_in[12];
    const float* l2a_whh = (const float*)d_in[13];
    const float* l2a_bih = (const float*)d_in[14];
    const float* l2a_bhh = (const float*)d_in[15];
    const float* l1m_wih = (const float*)d_in[16];
    const float* l1m_whh = (const float*)d_in[17];
    const float* l1m_bih = (const float*)d_in[18];
    const float* l1m_bhh = (const float*)d_in[19];
    const float* l2m_wih = (const float*)d_in[20];
    const float* l2m_whh = (const float*)d_in[21];
    const float* l2m_bih = (const float*)d_in[22];
    const float* l2m_bhh = (const float*)d_in[23];
    const float* fc1_w   = (const float*)d_in[24];
    const float* fc1_b   = (const float*)d_in[25];
    const float* fc2_w   = (const float*)d_in[26];
    const float* fc2_b   = (const float*)d_in[27];

    char* p = (char*)d_ws;
    uint16_t* in1_nhwc = (uint16_t*)p;             // 64MB  [256][1024][128] bf16
    float*    part     = (float*)p;                // 32MB alias (used after conv1 done)
    p += (size_t)64 << 20;
    uint16_t* c1out    = (uint16_t*)p; p += (size_t)32 << 20;   // [256][1024][64] NHWC bf16
    uint16_t* mbuf16   = (uint16_t*)p; p += (size_t)32 << 20;   // [256][64][1024] NCHW bf16
    uint16_t* ftflat16 = (uint16_t*)p; p += (size_t)32 << 20;   // [256][65536] bf16
    uint16_t* wpack1   = (uint16_t*)p; p += 256 * 1024;         // [64][1152] bf16
    uint16_t* wpack2   = (uint16_t*)p; p += 128 * 1024;         // [64][576] bf16
    float* hbuf = (float*)p; p += (size_t)2 << 20;              // [512][1024]
    float* inm  = (float*)p; p += (size_t)1 << 20;              // [t][b][1024]
    float* ina  = (float*)p; p += (size_t)1 << 20;
    float* gxm  = (float*)p; p += (size_t)2 << 20;              // [256][2048]
    float* gxa  = (float*)p; p += (size_t)2 << 20;
    float* w2m  = (float*)p; p += (size_t)4 << 20;              // [2048][512]
    float* b2m  = (float*)p; p += 8192;
    float* st   = (float*)p;                                    // 320KB states
    float* s1m  = st;
    float* s1a  = s1m + 16384;
    float* s2a  = s1a + 16384;
    float* c1m  = s2a + 16384;
    float* c1a  = c1m + 8192;
    float* c2m  = c1a + 8192;
    float* c2a  = c2m + 8192;

    float* outp = (float*)d_out;
    float* alpha_out = outp + 524288;

    hipMemsetAsync(st, 0, 81920 * sizeof(float), stream);

    // prep
    cvt_flat_kernel<<<8192, 256, 0, stream>>>(f_t, ftflat16, 16777216);
    nhwc_kernel<<<dim3(16, 256), 256, 0, stream>>>(f_t, f_t_1, in1_nhwc);
    wpack_kernel<<<288, 256, 0, stream>>>(conv1_w, conv2_w, wpack1, wpack2);

    // convs (MFMA implicit GEMM)
    conv_mfma_kernel<128, false><<<dim3(8, 256), 256, 0, stream>>>(
        in1_nhwc, wpack1, conv1_b, c1out);
    conv_mfma_kernel<64, true><<<dim3(8, 256), 256, 0, stream>>>(
        c1out, wpack2, conv2_b, mbuf16);

    // fc1 (MFMA, split-K=16) -- part aliases in1_nhwc (conv1 already consumed it)
    fc1_mfma_kernel<<<dim3(4, 8, 16), 256, 0, stream>>>(mbuf16, ftflat16, fc1_w, part);
    fc1_reduce_kernel<<<2048, 256, 0, stream>>>(part, fc1_b, hbuf);

    fc2_att_kernel<<<dim3(8, 8), 256, 0, stream>>>(hbuf, fc2_w, fc2_b, att1, att2,
                                                   alpha_out, inm, ina);

    gx_gemm_kernel<<<dim3(4, 32, 2), 256, 0, stream>>>(inm, ina,
                                                       l1m_wih, l1m_bih, l1m_bhh,
                                                       l1a_wih, l1a_bih, l1a_bhh,
                                                       gxm, gxa);
    w2sum_kernel<<<4096, 256, 0, stream>>>(l2m_wih, l2m_whh, l2m_bih, l2m_bhh, w2m, b2m);

    for (int t = 0; t < 16; ++t) {
        const float* s1m_in = s1m + (t & 1) * 8192;
        float*       s1m_o  = s1m + ((t + 1) & 1) * 8192;
        const float* s1a_in = s1a + (t & 1) * 8192;
        float*       s1a_o  = s1a + ((t + 1) & 1) * 8192;
        const float* s2a_in = s2a + (t & 1) * 8192;
        float*       s2a_o  = s2a + ((t + 1) & 1) * 8192;
        lstm_stage1_kernel<<<dim3(32, 2), 256, 0, stream>>>(
            t, gxm, gxa, l1m_whh, l1a_whh,
            s1m_in, s1m_o, s1a_in, s1a_o, c1m, c1a, outp);
        lstm_stage2_kernel<<<dim3(32, 2), 256, 0, stream>>>(
            t, w2m, b2m, l2a_wih, l2a_whh, l2a_bih, l2a_bhh,
            s1m_o, s1a_o, s2a_in, s2a_o, c2m, c2a, outp);
    }
}